// Round 12
// baseline (294.527 us; speedup 1.0000x reference)
//
#include <hip/hip_runtime.h>
#include <hip/hip_cooperative_groups.h>

namespace cg = cooperative_groups;

// FairINV 2-layer GCN + linear head — linear collapse + binned propagation.
//   w2c = W2@Wc; w1c = W1@w2c; c1 = b1.w2c; c2 = b2.Wc + bc      (prep, 1 block)
//   gemv_bin: z0 = x@w1c (GEMV units) || bin edges by bucket dst>>6 (bin units)
//   tail: deg->dinv -> z1 = P(z0)+c1 -> out = P(z1)+c2
// Tail is ONE cooperative kernel (782 slim blocks, records register-resident across
// two grid.sync()s) with a checked fallback to the 3-kernel path if the coop
// launch is rejected (R11 lesson: never assume the coop launch succeeded).
// P(z)[n] = dinv[n]*sum_e(ew_e*dinv[src_e]*z[src_e]) + dinv[n]^2*z[n]
// N=50000, E=800000, IN=256, HID=128, OUT=1. All arithmetic f32.

static constexpr int NN   = 50000;
static constexpr int NE   = 800000;
static constexpr int IND  = 256;
static constexpr int HD   = 128;
static constexpr int NNP  = 50048;

static constexpr int NBUK = 782;            // ceil(NN/64); bucket = dst >> 6
static constexpr int BCAP = 1536;           // 6 records/thread; mean 1024, +16 sigma
static constexpr int RPT  = BCAP / 256;     // register record slots per thread
static constexpr int BIN_BLOCKS  = 256;
static constexpr int EPB         = NE / BIN_BLOCKS;   // 3125 (exact)
static constexpr int SLOTS       = (EPB + 255) / 256; // 13 staging slots/thread
static constexpr int GEMV_BLOCKS = 3125;              // 16 nodes per block

// ---------------- prep: fold weights + zero bucket cursors (one block) ----------------

__global__ __launch_bounds__(256) void prep_kernel(
        const float* __restrict__ W1, const float* __restrict__ b1,
        const float* __restrict__ W2, const float* __restrict__ b2,
        const float* __restrict__ Wc, const float* __restrict__ bc,
        float* __restrict__ w1c, float* __restrict__ consts,
        int* __restrict__ gcur) {
    __shared__ float s_w2c[HD];
    const int t = threadIdx.x;
    for (int i = t; i < NBUK; i += 256) gcur[i] = 0;
    if (t < HD) {
        float s = 0.f;
        for (int j = 0; j < HD; j++) s += W2[t * HD + j] * Wc[j];
        s_w2c[t] = s;
    }
    __syncthreads();
    {   // t in [0,256) == IND
        float s = 0.f;
        for (int k = 0; k < HD; k++) s += W1[t * HD + k] * s_w2c[k];
        w1c[t] = s;
    }
    if (t == 0) {
        float c1 = 0.f, c2 = 0.f;
        for (int k = 0; k < HD; k++) c1 += b1[k] * s_w2c[k];
        for (int j = 0; j < HD; j++) c2 += b2[j] * Wc[j];
        consts[0] = c1;
        consts[1] = c2 + bc[0];
    }
}

// ---------------- fused GEMV (z0 = x @ w1c) + contention-free edge binning ----------

__global__ __launch_bounds__(256) void gemv_bin(
        const float* __restrict__ x, const float* __restrict__ w1c,
        float* __restrict__ z0,
        const int* __restrict__ src, const int* __restrict__ dst,
        const float* __restrict__ ew,
        int* __restrict__ gcur, uint2* __restrict__ bins) {
    __shared__ int hist[NBUK];
    __shared__ int cur[NBUK];

    if (blockIdx.x < GEMV_BLOCKS) {
        const int wid  = threadIdx.x >> 6;
        const int lane = threadIdx.x & 63;
        const int base = blockIdx.x * 16 + wid * 4;
        const float4 wv = ((const float4*)w1c)[lane];
#pragma unroll
        for (int g = 0; g < 4; g++) {
            const int n = base + g;
            if (n >= NN) break;
            const float4 xv = *((const float4*)(x + (size_t)n * IND) + lane);
            float p = xv.x * wv.x + xv.y * wv.y + xv.z * wv.z + xv.w * wv.w;
#pragma unroll
            for (int off = 32; off; off >>= 1) p += __shfl_down(p, off);
            if (lane == 0) z0[n] = p;
        }
    } else {
        const int t    = threadIdx.x;
        const int base = (blockIdx.x - GEMV_BLOCKS) * EPB;
        uint  key[SLOTS];
        float wv[SLOTS];
        for (int i = t; i < NBUK; i += 256) hist[i] = 0;
        __syncthreads();
#pragma unroll
        for (int k = 0; k < SLOTS; k++) {
            const int off = k * 256 + t;
            if (off < EPB) {
                const int e = base + off;
                const int d = dst[e];
                const int b = d >> 6;
                key[k] = (uint)src[e] | (((uint)d & 63u) << 16) | ((uint)b << 22);
                wv[k]  = ew[e];
                atomicAdd(&hist[b], 1);
            } else {
                key[k] = 0xFFFFFFFFu;
            }
        }
        __syncthreads();
        for (int i = t; i < NBUK; i += 256) {
            const int h = hist[i];
            cur[i] = h ? atomicAdd(&gcur[i], h) : 0;
        }
        __syncthreads();
#pragma unroll
        for (int k = 0; k < SLOTS; k++) {
            if (key[k] != 0xFFFFFFFFu) {
                const int b = key[k] >> 22;
                const int p = atomicAdd(&cur[b], 1);
                if (p < BCAP)
                    bins[(size_t)b * BCAP + p] =
                        make_uint2(key[k] & 0x3FFFFFu, __float_as_uint(wv[k]));
            }
        }
    }
}

// ---------------- cooperative tail: deg/dinv -> prop1 -> prop2 ----------------
// 782 slim blocks (records register-resident across the 2 grid.sync()s).

__global__ __launch_bounds__(256, 4) void tail_coop(
        const int* __restrict__ gcur, const uint2* __restrict__ bins,
        const float* __restrict__ z0, const float* __restrict__ consts,
        float2* __restrict__ dz0, float2* __restrict__ dz1,
        float* __restrict__ out) {
    cg::grid_group grid = cg::this_grid();
    __shared__ float acc[64];
    const int b = blockIdx.x;       // 0..NBUK-1 exactly
    const int t = threadIdx.x;

    // ---- P2: records -> registers; deg -> dinv; dz0 = {dinv, z0} ----
    uint  rk[RPT];
    float rw[RPT];
    if (t < 64) acc[t] = 0.f;
    __syncthreads();
    const int cnt = min(gcur[b], BCAP);
#pragma unroll
    for (int k = 0; k < RPT; k++) {
        const int r = k * 256 + t;
        if (r < cnt) {
            const uint2 q = bins[(size_t)b * BCAP + r];
            rk[k] = q.x;
            rw[k] = __uint_as_float(q.y);
            atomicAdd(&acc[(q.x >> 16) & 63u], rw[k]);
        } else {
            rk[k] = 0xFFFFFFFFu;
        }
    }
    __syncthreads();
    if (t < 64) {
        const int n = b * 64 + t;
        if (n < NN) dz0[n] = make_float2(rsqrtf(acc[t] + 1.0f), z0[n]);
    }
    __threadfence();
    grid.sync();

    // ---- P3: z1 = P(z0) + c1 ----
    if (t < 64) acc[t] = 0.f;
    __syncthreads();
#pragma unroll
    for (int k = 0; k < RPT; k++) {
        if (rk[k] != 0xFFFFFFFFu) {
            const float2 sz = dz0[rk[k] & 0xFFFFu];   // {dinv[s], z0[s]}
            atomicAdd(&acc[(rk[k] >> 16) & 63u], rw[k] * sz.x * sz.y);
        }
    }
    __syncthreads();
    if (t < 64) {
        const int n = b * 64 + t;
        if (n < NN) {
            const float2 me = dz0[n];
            dz1[n] = make_float2(me.x, acc[t] * me.x + me.y * me.x * me.x + consts[0]);
        }
    }
    __threadfence();
    grid.sync();

    // ---- P4: out = P(z1) + c2 ----
    if (t < 64) acc[t] = 0.f;
    __syncthreads();
#pragma unroll
    for (int k = 0; k < RPT; k++) {
        if (rk[k] != 0xFFFFFFFFu) {
            const float2 sz = dz1[rk[k] & 0xFFFFu];   // {dinv[s], z1[s]}
            atomicAdd(&acc[(rk[k] >> 16) & 63u], rw[k] * sz.x * sz.y);
        }
    }
    __syncthreads();
    if (t < 64) {
        const int n = b * 64 + t;
        if (n < NN) {
            const float2 me = dz1[n];
            out[n] = acc[t] * me.x + me.y * me.x * me.x + consts[1];
        }
    }
}

// ---------------- fallback kernels (R10-proven) ----------------

__global__ __launch_bounds__(256) void bindeg_kernel(
        const int* __restrict__ gcur, const uint2* __restrict__ bins,
        const float* __restrict__ z0, float2* __restrict__ dz0) {
    __shared__ float acc[64];
    const int b = blockIdx.x, t = threadIdx.x;
    if (t < 64) acc[t] = 0.f;
    __syncthreads();
    const int cnt = min(gcur[b], BCAP);
    for (int r = t; r < cnt; r += 256) {
        const uint2 q = bins[(size_t)b * BCAP + r];
        atomicAdd(&acc[(q.x >> 16) & 63u], __uint_as_float(q.y));
    }
    __syncthreads();
    if (t < 64) {
        const int n = b * 64 + t;
        if (n < NN) dz0[n] = make_float2(rsqrtf(acc[t] + 1.0f), z0[n]);
    }
}

template<bool LAST>
__global__ __launch_bounds__(256) void prop_kernel(
        const int* __restrict__ gcur, const uint2* __restrict__ bins,
        const float2* __restrict__ dzin, const float* __restrict__ consts,
        int cidx, float2* __restrict__ dzout, float* __restrict__ fout) {
    __shared__ float acc[64];
    const int b = blockIdx.x, t = threadIdx.x;
    if (t < 64) acc[t] = 0.f;
    __syncthreads();
    const int cnt = min(gcur[b], BCAP);
    for (int r = t; r < cnt; r += 256) {
        const uint2 q = bins[(size_t)b * BCAP + r];
        const float2 sz = dzin[q.x & 0xFFFFu];
        atomicAdd(&acc[(q.x >> 16) & 63u], __uint_as_float(q.y) * sz.x * sz.y);
    }
    __syncthreads();
    if (t < 64) {
        const int n = b * 64 + t;
        if (n < NN) {
            const float2 me = dzin[n];
            const float v = acc[t] * me.x + me.y * me.x * me.x + consts[cidx];
            if (LAST) fout[n] = v;
            else      dzout[n] = make_float2(me.x, v);
        }
    }
}

// ---------------- launch ----------------

extern "C" void kernel_launch(void* const* d_in, const int* in_sizes, int n_in,
                              void* d_out, int out_size, void* d_ws, size_t ws_size,
                              hipStream_t stream) {
    const float* x   = (const float*)d_in[0];
    const int*   ei  = (const int*)d_in[1];     // [2][E] int32
    const float* ew  = (const float*)d_in[2];
    const float* W1  = (const float*)d_in[3];
    const float* b1  = (const float*)d_in[4];
    const float* W2  = (const float*)d_in[5];
    const float* b2  = (const float*)d_in[6];
    const float* Wc  = (const float*)d_in[7];
    const float* bc  = (const float*)d_in[8];
    const int* src = ei;
    const int* dst = ei + NE;
    float* out = (float*)d_out;

    // workspace layout (~11.1 MB)
    uint2*  bins   = (uint2*)d_ws;                           // NBUK*BCAP uint2 (9.6 MB)
    float2* dz0    = (float2*)(bins + (size_t)NBUK * BCAP);  // NNP float2
    float2* dz1    = dz0 + NNP;                              // NNP float2
    float*  z0     = (float*)(dz1 + NNP);                    // NNP f32
    float*  w1c    = z0 + NNP;                               // 256 f32
    float*  consts = w1c + 256;                              // 2 f32 {c1, c2}
    int*    gcur   = (int*)(consts + 64);                    // NBUK int

    // ---- fold weights + zero cursors ----
    prep_kernel<<<1, 256, 0, stream>>>(W1, b1, W2, b2, Wc, bc, w1c, consts, gcur);

    // ---- z0 = x @ w1c fused with edge binning ----
    gemv_bin<<<GEMV_BLOCKS + BIN_BLOCKS, 256, 0, stream>>>(
        x, w1c, z0, src, dst, ew, gcur, bins);

    // ---- tail: cooperative (checked), else 3-kernel fallback ----
    void* args[] = {(void*)&gcur, (void*)&bins, (void*)&z0, (void*)&consts,
                    (void*)&dz0, (void*)&dz1, (void*)&out};
    hipError_t cerr = hipLaunchCooperativeKernel((const void*)tail_coop, dim3(NBUK),
                                                 dim3(256), args, 0, stream);
    if (cerr != hipSuccess) {
        bindeg_kernel<<<NBUK, 256, 0, stream>>>(gcur, bins, z0, dz0);
        prop_kernel<false><<<NBUK, 256, 0, stream>>>(gcur, bins, dz0, consts, 0, dz1, nullptr);
        prop_kernel<true><<<NBUK, 256, 0, stream>>>(gcur, bins, dz1, consts, 1, nullptr, out);
    }
}

// Round 13
// 77.048 us; speedup vs baseline: 3.8226x; 3.8226x over previous
//
#include <hip/hip_runtime.h>

// FairINV 2-layer GCN + linear head — linear collapse + bucket-binned propagation.
//   w2c = W2@Wc; w1c = W1@w2c; c1 = b1.w2c; c2 = b2.Wc + bc      (prep, 1 block)
//   gemv_bin: bin edges by bucket dst>>6 (800 bin units, FIRST) || z0 = x@w1c (GEMV)
//   bindeg:   bins -> deg -> dinv; dz0 = {dinv, z0}
//   prop1:    z1 = P(z0)+c1      prop2: out = P(z1)+c2
// P(z)[n] = dinv[n]*sum_e(ew_e*dinv[src_e]*z[src_e]) + dinv[n]^2*z[n]
// R12 lesson: cooperative grid.sync costs ~80+ µs/barrier here — separate launches win.
// R10 lesson baked in: bin units first + 800-way binning to shorten the bin critical path.
// N=50000, E=800000, IN=256, HID=128, OUT=1. All arithmetic f32.

static constexpr int NN   = 50000;
static constexpr int NE   = 800000;
static constexpr int IND  = 256;
static constexpr int HD   = 128;
static constexpr int NNP  = 50048;

static constexpr int NBUK = 782;            // ceil(NN/64); bucket = dst >> 6
static constexpr int BCAP = 1536;           // mean fill 1024, +16 sigma
static constexpr int BIN_BLOCKS  = 800;
static constexpr int EPB         = NE / BIN_BLOCKS;   // 1000 (exact)
static constexpr int SLOTS       = (EPB + 255) / 256; // 4 staging slots/thread
static constexpr int GEMV_BLOCKS = 3125;              // 16 nodes per block

// ---------------- prep: fold weights + zero bucket cursors (one block) ----------------

__global__ __launch_bounds__(256) void prep_kernel(
        const float* __restrict__ W1, const float* __restrict__ b1,
        const float* __restrict__ W2, const float* __restrict__ b2,
        const float* __restrict__ Wc, const float* __restrict__ bc,
        float* __restrict__ w1c, float* __restrict__ consts,
        int* __restrict__ gcur) {
    __shared__ float s_w2c[HD];
    const int t = threadIdx.x;
    for (int i = t; i < NBUK; i += 256) gcur[i] = 0;
    if (t < HD) {
        float s = 0.f;
        for (int j = 0; j < HD; j++) s += W2[t * HD + j] * Wc[j];
        s_w2c[t] = s;
    }
    __syncthreads();
    {   // t in [0,256) == IND
        float s = 0.f;
        for (int k = 0; k < HD; k++) s += W1[t * HD + k] * s_w2c[k];
        w1c[t] = s;
    }
    if (t == 0) {
        float c1 = 0.f, c2 = 0.f;
        for (int k = 0; k < HD; k++) c1 += b1[k] * s_w2c[k];
        for (int j = 0; j < HD; j++) c2 += b2[j] * Wc[j];
        consts[0] = c1;
        consts[1] = c2 + bc[0];
    }
}

// ---------------- fused edge binning (first) + GEMV (z0 = x @ w1c) ----------------
// Bin blocks [0,800): stage 1000 edges in regs, LDS histogram over 782 buckets,
// reserve ranges (1 global atomic per block-bucket), write 8B records {key, ew_f32}.
// GEMV blocks: one wave per node, lane reads float4 of the x-row.

__global__ __launch_bounds__(256) void gemv_bin(
        const float* __restrict__ x, const float* __restrict__ w1c,
        float* __restrict__ z0,
        const int* __restrict__ src, const int* __restrict__ dst,
        const float* __restrict__ ew,
        int* __restrict__ gcur, uint2* __restrict__ bins) {
    __shared__ int hist[NBUK];
    __shared__ int cur[NBUK];

    if (blockIdx.x < BIN_BLOCKS) {
        const int t    = threadIdx.x;
        const int base = blockIdx.x * EPB;
        uint  key[SLOTS];
        float wv[SLOTS];
        for (int i = t; i < NBUK; i += 256) hist[i] = 0;
        __syncthreads();
#pragma unroll
        for (int k = 0; k < SLOTS; k++) {
            const int off = k * 256 + t;
            if (off < EPB) {
                const int e = base + off;
                const int d = dst[e];
                const int b = d >> 6;
                key[k] = (uint)src[e] | (((uint)d & 63u) << 16) | ((uint)b << 22);
                wv[k]  = ew[e];
                atomicAdd(&hist[b], 1);
            } else {
                key[k] = 0xFFFFFFFFu;
            }
        }
        __syncthreads();
        for (int i = t; i < NBUK; i += 256) {
            const int h = hist[i];
            cur[i] = h ? atomicAdd(&gcur[i], h) : 0;
        }
        __syncthreads();
#pragma unroll
        for (int k = 0; k < SLOTS; k++) {
            if (key[k] != 0xFFFFFFFFu) {
                const int b = key[k] >> 22;
                const int p = atomicAdd(&cur[b], 1);
                if (p < BCAP)
                    bins[(size_t)b * BCAP + p] =
                        make_uint2(key[k] & 0x3FFFFFu, __float_as_uint(wv[k]));
            }
        }
    } else {
        const int wid  = threadIdx.x >> 6;
        const int lane = threadIdx.x & 63;
        const int base = (blockIdx.x - BIN_BLOCKS) * 16 + wid * 4;
        const float4 wv = ((const float4*)w1c)[lane];
#pragma unroll
        for (int g = 0; g < 4; g++) {
            const int n = base + g;
            if (n >= NN) break;
            const float4 xv = *((const float4*)(x + (size_t)n * IND) + lane);
            float p = xv.x * wv.x + xv.y * wv.y + xv.z * wv.z + xv.w * wv.w;
#pragma unroll
            for (int off = 32; off; off >>= 1) p += __shfl_down(p, off);
            if (lane == 0) z0[n] = p;
        }
    }
}

// ---------------- bindeg: bins -> dinv, interleave dz0 = {dinv, z0} ----------------

__global__ __launch_bounds__(256) void bindeg_kernel(
        const int* __restrict__ gcur, const uint2* __restrict__ bins,
        const float* __restrict__ z0, float2* __restrict__ dz0) {
    __shared__ float acc[64];
    const int b = blockIdx.x, t = threadIdx.x;
    if (t < 64) acc[t] = 0.f;
    __syncthreads();
    const int cnt = min(gcur[b], BCAP);
    for (int r = t; r < cnt; r += 256) {
        const uint2 q = bins[(size_t)b * BCAP + r];
        atomicAdd(&acc[(q.x >> 16) & 63u], __uint_as_float(q.y));
    }
    __syncthreads();
    if (t < 64) {
        const int n = b * 64 + t;
        if (n < NN) dz0[n] = make_float2(rsqrtf(acc[t] + 1.0f), z0[n]);
    }
}

// ---------------- prop: one bucket per block, LDS 64-slot accumulator ----------------
// zout[n] = acc[n]*dinv[n] + z[n]*dinv[n]^2 + consts[cidx]

template<bool LAST>
__global__ __launch_bounds__(256) void prop_kernel(
        const int* __restrict__ gcur, const uint2* __restrict__ bins,
        const float2* __restrict__ dzin, const float* __restrict__ consts,
        int cidx, float2* __restrict__ dzout, float* __restrict__ fout) {
    __shared__ float acc[64];
    const int b = blockIdx.x, t = threadIdx.x;
    if (t < 64) acc[t] = 0.f;
    __syncthreads();
    const int cnt = min(gcur[b], BCAP);
    for (int r = t; r < cnt; r += 256) {
        const uint2 q = bins[(size_t)b * BCAP + r];
        const float2 sz = dzin[q.x & 0xFFFFu];          // {dinv[s], z[s]} — L2-resident
        atomicAdd(&acc[(q.x >> 16) & 63u], __uint_as_float(q.y) * sz.x * sz.y);
    }
    __syncthreads();
    if (t < 64) {
        const int n = b * 64 + t;
        if (n < NN) {
            const float2 me = dzin[n];
            const float v = acc[t] * me.x + me.y * me.x * me.x + consts[cidx];
            if (LAST) fout[n] = v;
            else      dzout[n] = make_float2(me.x, v);
        }
    }
}

// ---------------- launch ----------------

extern "C" void kernel_launch(void* const* d_in, const int* in_sizes, int n_in,
                              void* d_out, int out_size, void* d_ws, size_t ws_size,
                              hipStream_t stream) {
    const float* x   = (const float*)d_in[0];
    const int*   ei  = (const int*)d_in[1];     // [2][E] int32
    const float* ew  = (const float*)d_in[2];
    const float* W1  = (const float*)d_in[3];
    const float* b1  = (const float*)d_in[4];
    const float* W2  = (const float*)d_in[5];
    const float* b2  = (const float*)d_in[6];
    const float* Wc  = (const float*)d_in[7];
    const float* bc  = (const float*)d_in[8];
    const int* src = ei;
    const int* dst = ei + NE;
    float* out = (float*)d_out;

    // workspace layout (~11.1 MB)
    uint2*  bins   = (uint2*)d_ws;                           // NBUK*BCAP uint2 (9.6 MB)
    float2* dz0    = (float2*)(bins + (size_t)NBUK * BCAP);  // NNP float2
    float2* dz1    = dz0 + NNP;                              // NNP float2
    float*  z0     = (float*)(dz1 + NNP);                    // NNP f32
    float*  w1c    = z0 + NNP;                               // 256 f32
    float*  consts = w1c + 256;                              // 2 f32 {c1, c2}
    int*    gcur   = (int*)(consts + 64);                    // NBUK int

    // ---- fold weights + zero cursors ----
    prep_kernel<<<1, 256, 0, stream>>>(W1, b1, W2, b2, Wc, bc, w1c, consts, gcur);

    // ---- edge binning (first blocks) overlapped with z0 = x @ w1c ----
    gemv_bin<<<BIN_BLOCKS + GEMV_BLOCKS, 256, 0, stream>>>(
        x, w1c, z0, src, dst, ew, gcur, bins);

    // ---- dinv from bins, build {dinv, z0} ----
    bindeg_kernel<<<NBUK, 256, 0, stream>>>(gcur, bins, z0, dz0);

    // ---- two scalar propagations ----
    prop_kernel<false><<<NBUK, 256, 0, stream>>>(gcur, bins, dz0, consts, 0, dz1, nullptr);
    prop_kernel<true><<<NBUK, 256, 0, stream>>>(gcur, bins, dz1, consts, 1, nullptr, out);
}

// Round 14
// 71.032 us; speedup vs baseline: 4.1464x; 1.0847x over previous
//
#include <hip/hip_runtime.h>

// FairINV 2-layer GCN + linear head — linear collapse + bucket-binned propagation.
//   w2c = W2@Wc; w1c = W1@w2c; c1 = b1.w2c; c2 = b2.Wc + bc      (prep, 1 block)
//   gemv_bin: bin edges by bucket dst>>6 (128 bin units, two-pass, FIRST)
//             || z0 = x@w1c (GEMV, branchless 4-row ILP)
//   bindeg:   bins -> deg -> dinv; dz0 = {dinv, z0}
//   prop1:    z1 = P(z0)+c1      prop2: out = P(z1)+c2
// P(z)[n] = dinv[n]*sum_e(ew_e*dinv[src_e]*z[src_e]) + dinv[n]^2*z[n]
// R13 lesson: per-(block,bucket) run length rules the binning write drain —
// 128 blocks give ~8-record (64B, full-line) runs; two-pass reads avoid the
// register-staging pressure that killed R11.
// R12 lesson: no cooperative grid.sync (~80+ µs/barrier). Separate launches.
// N=50000, E=800000, IN=256, HID=128, OUT=1. All arithmetic f32.

static constexpr int NN   = 50000;
static constexpr int NE   = 800000;
static constexpr int IND  = 256;
static constexpr int HD   = 128;
static constexpr int NNP  = 50048;

static constexpr int NBUK = 782;            // ceil(NN/64); bucket = dst >> 6
static constexpr int BCAP = 1536;           // mean fill 1024, +16 sigma
static constexpr int BIN_BLOCKS  = 128;
static constexpr int EPB         = NE / BIN_BLOCKS;   // 6250 (exact)
static constexpr int GEMV_BLOCKS = 3125;              // 16 nodes per block (exact)

// ---------------- prep: fold weights + zero bucket cursors (one block) ----------------

__global__ __launch_bounds__(256) void prep_kernel(
        const float* __restrict__ W1, const float* __restrict__ b1,
        const float* __restrict__ W2, const float* __restrict__ b2,
        const float* __restrict__ Wc, const float* __restrict__ bc,
        float* __restrict__ w1c, float* __restrict__ consts,
        int* __restrict__ gcur) {
    __shared__ float s_w2c[HD];
    const int t = threadIdx.x;
    for (int i = t; i < NBUK; i += 256) gcur[i] = 0;
    if (t < HD) {
        float s = 0.f;
        for (int j = 0; j < HD; j++) s += W2[t * HD + j] * Wc[j];
        s_w2c[t] = s;
    }
    __syncthreads();
    {   // t in [0,256) == IND
        float s = 0.f;
        for (int k = 0; k < HD; k++) s += W1[t * HD + k] * s_w2c[k];
        w1c[t] = s;
    }
    if (t == 0) {
        float c1 = 0.f, c2 = 0.f;
        for (int k = 0; k < HD; k++) c1 += b1[k] * s_w2c[k];
        for (int j = 0; j < HD; j++) c2 += b2[j] * Wc[j];
        consts[0] = c1;
        consts[1] = c2 + bc[0];
    }
}

// ---------------- fused edge binning (two-pass, first) + GEMV ----------------
// Bin blocks [0,128): pass A streams dst -> LDS histogram; reserve global ranges
// (one atomic per block-bucket, ~8 records = 64B runs); pass B re-reads src/dst/ew
// (L2/L3-hot) and writes records through LDS cursors.
// GEMV blocks: one wave per 4 nodes, branchless, 4 loads up-front (ILP).

__global__ __launch_bounds__(256) void gemv_bin(
        const float* __restrict__ x, const float* __restrict__ w1c,
        float* __restrict__ z0,
        const int* __restrict__ src, const int* __restrict__ dst,
        const float* __restrict__ ew,
        int* __restrict__ gcur, uint2* __restrict__ bins) {
    __shared__ int hist[NBUK];
    __shared__ int cur[NBUK];

    if (blockIdx.x < BIN_BLOCKS) {
        const int t    = threadIdx.x;
        const int base = blockIdx.x * EPB;
        for (int i = t; i < NBUK; i += 256) hist[i] = 0;
        __syncthreads();
        // ---- pass A: histogram ----
        for (int off = t; off < EPB; off += 256)
            atomicAdd(&hist[dst[base + off] >> 6], 1);
        __syncthreads();
        // ---- reserve ranges ----
        for (int i = t; i < NBUK; i += 256) {
            const int h = hist[i];
            cur[i] = h ? atomicAdd(&gcur[i], h) : 0;
        }
        __syncthreads();
        // ---- pass B: place records ----
        for (int off = t; off < EPB; off += 256) {
            const int e = base + off;
            const int d = dst[e];
            const int b = d >> 6;
            const int p = atomicAdd(&cur[b], 1);
            if (p < BCAP)
                bins[(size_t)b * BCAP + p] =
                    make_uint2((uint)src[e] | (((uint)d & 63u) << 16),
                               __float_as_uint(ew[e]));
        }
    } else {
        const int wid  = threadIdx.x >> 6;
        const int lane = threadIdx.x & 63;
        const int n0   = (blockIdx.x - BIN_BLOCKS) * 16 + wid * 4;   // exact: no bounds
        const float4 wv = ((const float4*)w1c)[lane];
        const float4 x0 = *((const float4*)(x + (size_t)(n0 + 0) * IND) + lane);
        const float4 x1 = *((const float4*)(x + (size_t)(n0 + 1) * IND) + lane);
        const float4 x2 = *((const float4*)(x + (size_t)(n0 + 2) * IND) + lane);
        const float4 x3 = *((const float4*)(x + (size_t)(n0 + 3) * IND) + lane);
        float p0 = x0.x * wv.x + x0.y * wv.y + x0.z * wv.z + x0.w * wv.w;
        float p1 = x1.x * wv.x + x1.y * wv.y + x1.z * wv.z + x1.w * wv.w;
        float p2 = x2.x * wv.x + x2.y * wv.y + x2.z * wv.z + x2.w * wv.w;
        float p3 = x3.x * wv.x + x3.y * wv.y + x3.z * wv.z + x3.w * wv.w;
#pragma unroll
        for (int off = 32; off; off >>= 1) {
            p0 += __shfl_down(p0, off);
            p1 += __shfl_down(p1, off);
            p2 += __shfl_down(p2, off);
            p3 += __shfl_down(p3, off);
        }
        if (lane == 0) {
            z0[n0 + 0] = p0;
            z0[n0 + 1] = p1;
            z0[n0 + 2] = p2;
            z0[n0 + 3] = p3;
        }
    }
}

// ---------------- bindeg: bins -> dinv, interleave dz0 = {dinv, z0} ----------------

__global__ __launch_bounds__(256) void bindeg_kernel(
        const int* __restrict__ gcur, const uint2* __restrict__ bins,
        const float* __restrict__ z0, float2* __restrict__ dz0) {
    __shared__ float acc[64];
    const int b = blockIdx.x, t = threadIdx.x;
    if (t < 64) acc[t] = 0.f;
    __syncthreads();
    const int cnt = min(gcur[b], BCAP);
    for (int r = t; r < cnt; r += 256) {
        const uint2 q = bins[(size_t)b * BCAP + r];
        atomicAdd(&acc[(q.x >> 16) & 63u], __uint_as_float(q.y));
    }
    __syncthreads();
    if (t < 64) {
        const int n = b * 64 + t;
        if (n < NN) dz0[n] = make_float2(rsqrtf(acc[t] + 1.0f), z0[n]);
    }
}

// ---------------- prop: one bucket per block, LDS 64-slot accumulator ----------------
// zout[n] = acc[n]*dinv[n] + z[n]*dinv[n]^2 + consts[cidx]

template<bool LAST>
__global__ __launch_bounds__(256) void prop_kernel(
        const int* __restrict__ gcur, const uint2* __restrict__ bins,
        const float2* __restrict__ dzin, const float* __restrict__ consts,
        int cidx, float2* __restrict__ dzout, float* __restrict__ fout) {
    __shared__ float acc[64];
    const int b = blockIdx.x, t = threadIdx.x;
    if (t < 64) acc[t] = 0.f;
    __syncthreads();
    const int cnt = min(gcur[b], BCAP);
    for (int r = t; r < cnt; r += 256) {
        const uint2 q = bins[(size_t)b * BCAP + r];
        const float2 sz = dzin[q.x & 0xFFFFu];          // {dinv[s], z[s]} — L2-resident
        atomicAdd(&acc[(q.x >> 16) & 63u], __uint_as_float(q.y) * sz.x * sz.y);
    }
    __syncthreads();
    if (t < 64) {
        const int n = b * 64 + t;
        if (n < NN) {
            const float2 me = dzin[n];
            const float v = acc[t] * me.x + me.y * me.x * me.x + consts[cidx];
            if (LAST) fout[n] = v;
            else      dzout[n] = make_float2(me.x, v);
        }
    }
}

// ---------------- launch ----------------

extern "C" void kernel_launch(void* const* d_in, const int* in_sizes, int n_in,
                              void* d_out, int out_size, void* d_ws, size_t ws_size,
                              hipStream_t stream) {
    const float* x   = (const float*)d_in[0];
    const int*   ei  = (const int*)d_in[1];     // [2][E] int32
    const float* ew  = (const float*)d_in[2];
    const float* W1  = (const float*)d_in[3];
    const float* b1  = (const float*)d_in[4];
    const float* W2  = (const float*)d_in[5];
    const float* b2  = (const float*)d_in[6];
    const float* Wc  = (const float*)d_in[7];
    const float* bc  = (const float*)d_in[8];
    const int* src = ei;
    const int* dst = ei + NE;
    float* out = (float*)d_out;

    // workspace layout (~11.1 MB)
    uint2*  bins   = (uint2*)d_ws;                           // NBUK*BCAP uint2 (9.6 MB)
    float2* dz0    = (float2*)(bins + (size_t)NBUK * BCAP);  // NNP float2
    float2* dz1    = dz0 + NNP;                              // NNP float2
    float*  z0     = (float*)(dz1 + NNP);                    // NNP f32
    float*  w1c    = z0 + NNP;                               // 256 f32
    float*  consts = w1c + 256;                              // 2 f32 {c1, c2}
    int*    gcur   = (int*)(consts + 64);                    // NBUK int

    // ---- fold weights + zero cursors ----
    prep_kernel<<<1, 256, 0, stream>>>(W1, b1, W2, b2, Wc, bc, w1c, consts, gcur);

    // ---- edge binning (first blocks, two-pass) overlapped with z0 = x @ w1c ----
    gemv_bin<<<BIN_BLOCKS + GEMV_BLOCKS, 256, 0, stream>>>(
        x, w1c, z0, src, dst, ew, gcur, bins);

    // ---- dinv from bins, build {dinv, z0} ----
    bindeg_kernel<<<NBUK, 256, 0, stream>>>(gcur, bins, z0, dz0);

    // ---- two scalar propagations ----
    prop_kernel<false><<<NBUK, 256, 0, stream>>>(gcur, bins, dz0, consts, 0, dz1, nullptr);
    prop_kernel<true><<<NBUK, 256, 0, stream>>>(gcur, bins, dz1, consts, 1, nullptr, out);
}

// Round 15
// 59.394 us; speedup vs baseline: 4.9588x; 1.1959x over previous
//
#include <hip/hip_runtime.h>

// FairINV 2-layer GCN + linear head — linear collapse + bucket-binned propagation.
//   w2c = W2@Wc; w1c = W1@w2c; c1 = b1.w2c; c2 = b2.Wc + bc      (prep, 1 block)
//   gemv_bin: bin edges by bucket dst>>8 (256 bin units, reg-staged, FIRST)
//             || z0 = x@w1c (GEMV, branchless 4-row ILP)
//   bindeg:   bins -> deg -> dinv; dz0 = {dinv, z0}     (196 blocks, 256-slot acc)
//   prop1:    z1 = P(z0)+c1      prop2: out = P(z1)+c2
// P(z)[n] = dinv[n]*sum_e(ew_e*dinv[src_e]*z[src_e]) + dinv[n]^2*z[n]
// R14 lesson: bin-tail parallelism matters as much as write-run length. 256 blocks
// x 196 coarse buckets gives runs of ~16 records (128B, full lines) AND a short
// parallel tail AND one-pass register staging. R12 lesson: no grid.sync.
// N=50000, E=800000, IN=256, HID=128, OUT=1. All arithmetic f32.

static constexpr int NN   = 50000;
static constexpr int NE   = 800000;
static constexpr int IND  = 256;
static constexpr int HD   = 128;
static constexpr int NNP  = 50048;

static constexpr int NBUK = 196;            // ceil(NN/256); bucket = dst >> 8
static constexpr int BCAP = 5120;           // mean fill 4096, +16 sigma
static constexpr int BIN_BLOCKS  = 256;
static constexpr int EPB         = NE / BIN_BLOCKS;   // 3125 (exact)
static constexpr int SLOTS       = (EPB + 255) / 256; // 13 staging slots/thread
static constexpr int GEMV_BLOCKS = 3125;              // 16 nodes per block (exact)

// ---------------- prep: fold weights + zero bucket cursors (one block) ----------------

__global__ __launch_bounds__(256) void prep_kernel(
        const float* __restrict__ W1, const float* __restrict__ b1,
        const float* __restrict__ W2, const float* __restrict__ b2,
        const float* __restrict__ Wc, const float* __restrict__ bc,
        float* __restrict__ w1c, float* __restrict__ consts,
        int* __restrict__ gcur) {
    __shared__ float s_w2c[HD];
    const int t = threadIdx.x;
    if (t < NBUK) gcur[t] = 0;
    if (t < HD) {
        float s = 0.f;
        for (int j = 0; j < HD; j++) s += W2[t * HD + j] * Wc[j];
        s_w2c[t] = s;
    }
    __syncthreads();
    {   // t in [0,256) == IND
        float s = 0.f;
        for (int k = 0; k < HD; k++) s += W1[t * HD + k] * s_w2c[k];
        w1c[t] = s;
    }
    if (t == 0) {
        float c1 = 0.f, c2 = 0.f;
        for (int k = 0; k < HD; k++) c1 += b1[k] * s_w2c[k];
        for (int j = 0; j < HD; j++) c2 += b2[j] * Wc[j];
        consts[0] = c1;
        consts[1] = c2 + bc[0];
    }
}

// ---------------- fused edge binning (reg-staged, first) + GEMV ----------------
// Bin blocks [0,256): stage 3125 edges in registers (one read pass), LDS histogram
// over 196 coarse buckets, reserve global ranges (1 atomic per block-bucket,
// ~16-record = 128B runs), write 8B records {src u16 | dloc u8 | buk u8, ew f32}.
// GEMV blocks: one wave per 4 nodes, branchless, 4 loads up-front (ILP).

__global__ __launch_bounds__(256) void gemv_bin(
        const float* __restrict__ x, const float* __restrict__ w1c,
        float* __restrict__ z0,
        const int* __restrict__ src, const int* __restrict__ dst,
        const float* __restrict__ ew,
        int* __restrict__ gcur, uint2* __restrict__ bins) {
    __shared__ int hist[NBUK];
    __shared__ int cur[NBUK];

    if (blockIdx.x < BIN_BLOCKS) {
        const int t    = threadIdx.x;
        const int base = blockIdx.x * EPB;
        uint  key[SLOTS];
        float wv[SLOTS];
        if (t < NBUK) hist[t] = 0;
        __syncthreads();
#pragma unroll
        for (int k = 0; k < SLOTS; k++) {
            const int off = k * 256 + t;
            if (off < EPB) {
                const int e = base + off;
                const int d = dst[e];
                const int b = d >> 8;
                key[k] = (uint)src[e] | (((uint)d & 255u) << 16) | ((uint)b << 24);
                wv[k]  = ew[e];
                atomicAdd(&hist[b], 1);
            } else {
                key[k] = 0xFFFFFFFFu;
            }
        }
        __syncthreads();
        if (t < NBUK) {
            const int h = hist[t];
            cur[t] = h ? atomicAdd(&gcur[t], h) : 0;
        }
        __syncthreads();
#pragma unroll
        for (int k = 0; k < SLOTS; k++) {
            if (key[k] != 0xFFFFFFFFu) {
                const int b = key[k] >> 24;
                const int p = atomicAdd(&cur[b], 1);
                if (p < BCAP)
                    bins[(size_t)b * BCAP + p] =
                        make_uint2(key[k] & 0xFFFFFFu, __float_as_uint(wv[k]));
            }
        }
    } else {
        const int wid  = threadIdx.x >> 6;
        const int lane = threadIdx.x & 63;
        const int n0   = (blockIdx.x - BIN_BLOCKS) * 16 + wid * 4;   // exact: no bounds
        const float4 wv = ((const float4*)w1c)[lane];
        const float4 x0 = *((const float4*)(x + (size_t)(n0 + 0) * IND) + lane);
        const float4 x1 = *((const float4*)(x + (size_t)(n0 + 1) * IND) + lane);
        const float4 x2 = *((const float4*)(x + (size_t)(n0 + 2) * IND) + lane);
        const float4 x3 = *((const float4*)(x + (size_t)(n0 + 3) * IND) + lane);
        float p0 = x0.x * wv.x + x0.y * wv.y + x0.z * wv.z + x0.w * wv.w;
        float p1 = x1.x * wv.x + x1.y * wv.y + x1.z * wv.z + x1.w * wv.w;
        float p2 = x2.x * wv.x + x2.y * wv.y + x2.z * wv.z + x2.w * wv.w;
        float p3 = x3.x * wv.x + x3.y * wv.y + x3.z * wv.z + x3.w * wv.w;
#pragma unroll
        for (int off = 32; off; off >>= 1) {
            p0 += __shfl_down(p0, off);
            p1 += __shfl_down(p1, off);
            p2 += __shfl_down(p2, off);
            p3 += __shfl_down(p3, off);
        }
        if (lane == 0) {
            z0[n0 + 0] = p0;
            z0[n0 + 1] = p1;
            z0[n0 + 2] = p2;
            z0[n0 + 3] = p3;
        }
    }
}

// ---------------- bindeg: bins -> dinv, interleave dz0 = {dinv, z0} ----------------
// one 256-node bucket per block, 256-slot LDS accumulator.

__global__ __launch_bounds__(256) void bindeg_kernel(
        const int* __restrict__ gcur, const uint2* __restrict__ bins,
        const float* __restrict__ z0, float2* __restrict__ dz0) {
    __shared__ float acc[256];
    const int b = blockIdx.x, t = threadIdx.x;
    acc[t] = 0.f;
    __syncthreads();
    const int cnt = min(gcur[b], BCAP);
    for (int r = t; r < cnt; r += 256) {
        const uint2 q = bins[(size_t)b * BCAP + r];
        atomicAdd(&acc[(q.x >> 16) & 255u], __uint_as_float(q.y));
    }
    __syncthreads();
    const int n = b * 256 + t;
    if (n < NN) dz0[n] = make_float2(rsqrtf(acc[t] + 1.0f), z0[n]);
}

// ---------------- prop: one bucket per block, 256-slot LDS accumulator ----------------
// zout[n] = acc[n]*dinv[n] + z[n]*dinv[n]^2 + consts[cidx]

template<bool LAST>
__global__ __launch_bounds__(256) void prop_kernel(
        const int* __restrict__ gcur, const uint2* __restrict__ bins,
        const float2* __restrict__ dzin, const float* __restrict__ consts,
        int cidx, float2* __restrict__ dzout, float* __restrict__ fout) {
    __shared__ float acc[256];
    const int b = blockIdx.x, t = threadIdx.x;
    acc[t] = 0.f;
    __syncthreads();
    const int cnt = min(gcur[b], BCAP);
    for (int r = t; r < cnt; r += 256) {
        const uint2 q = bins[(size_t)b * BCAP + r];
        const float2 sz = dzin[q.x & 0xFFFFu];          // {dinv[s], z[s]} — L2-resident
        atomicAdd(&acc[(q.x >> 16) & 255u], __uint_as_float(q.y) * sz.x * sz.y);
    }
    __syncthreads();
    const int n = b * 256 + t;
    if (n < NN) {
        const float2 me = dzin[n];
        const float v = acc[t] * me.x + me.y * me.x * me.x + consts[cidx];
        if (LAST) fout[n] = v;
        else      dzout[n] = make_float2(me.x, v);
    }
}

// ---------------- launch ----------------

extern "C" void kernel_launch(void* const* d_in, const int* in_sizes, int n_in,
                              void* d_out, int out_size, void* d_ws, size_t ws_size,
                              hipStream_t stream) {
    const float* x   = (const float*)d_in[0];
    const int*   ei  = (const int*)d_in[1];     // [2][E] int32
    const float* ew  = (const float*)d_in[2];
    const float* W1  = (const float*)d_in[3];
    const float* b1  = (const float*)d_in[4];
    const float* W2  = (const float*)d_in[5];
    const float* b2  = (const float*)d_in[6];
    const float* Wc  = (const float*)d_in[7];
    const float* bc  = (const float*)d_in[8];
    const int* src = ei;
    const int* dst = ei + NE;
    float* out = (float*)d_out;

    // workspace layout (~9.6 MB)
    uint2*  bins   = (uint2*)d_ws;                           // NBUK*BCAP uint2 (8.0 MB)
    float2* dz0    = (float2*)(bins + (size_t)NBUK * BCAP);  // NNP float2
    float2* dz1    = dz0 + NNP;                              // NNP float2
    float*  z0     = (float*)(dz1 + NNP);                    // NNP f32
    float*  w1c    = z0 + NNP;                               // 256 f32
    float*  consts = w1c + 256;                              // 2 f32 {c1, c2}
    int*    gcur   = (int*)(consts + 64);                    // NBUK int

    // ---- fold weights + zero cursors ----
    prep_kernel<<<1, 256, 0, stream>>>(W1, b1, W2, b2, Wc, bc, w1c, consts, gcur);

    // ---- edge binning (first blocks, reg-staged) overlapped with z0 = x @ w1c ----
    gemv_bin<<<BIN_BLOCKS + GEMV_BLOCKS, 256, 0, stream>>>(
        x, w1c, z0, src, dst, ew, gcur, bins);

    // ---- dinv from bins, build {dinv, z0} ----
    bindeg_kernel<<<NBUK, 256, 0, stream>>>(gcur, bins, z0, dz0);

    // ---- two scalar propagations ----
    prop_kernel<false><<<NBUK, 256, 0, stream>>>(gcur, bins, dz0, consts, 0, dz1, nullptr);
    prop_kernel<true><<<NBUK, 256, 0, stream>>>(gcur, bins, dz1, consts, 1, nullptr, out);
}